// Round 8
// baseline (1430.010 us; speedup 1.0000x reference)
//
#include <hip/hip_runtime.h>
#include <hip/hip_bf16.h>
#include <math.h>

// Problem constants
#define N_ROWS 512      // B*S
#define D_IN   512
#define E_EMB  256
#define H_DIM  512
#define G_DIM  2048
#define V_DIM  32000
#define IN_LD  1280     // Abuf row: [ x(512) | emb(256) | h(512) ]
#define K_STEPS 4
#define OOV_ID 1
#define TBK 64
#define EMB_SPLIT 50
#define EMB_CHUNK 640   // 50*640 = 32000
#define SEGSTRIDE 512   // stats row stride (500 used)

typedef __attribute__((ext_vector_type(4))) float f32x4;
typedef __attribute__((ext_vector_type(8))) short bf16x8;
typedef __attribute__((ext_vector_type(8))) _Float16 f16x8;

__device__ inline short f2b(float v) {
    __hip_bfloat16 h = __float2bfloat16(v);
    return *reinterpret_cast<short*>(&h);
}

// async global->LDS, 16B per lane; dest = ldsbase + lane*16 (wave-uniform base)
__device__ inline void gload_lds(const short* g, short* l) {
    __builtin_amdgcn_global_load_lds(
        (const __attribute__((address_space(1))) void*)g,
        (__attribute__((address_space(3))) void*)l, 16, 0, 0);
}

// ---------------------------------------------------------------------------
// MFMA GEMM: C(MxN) = A(MxK,bf16 rm) @ B(NxK,bf16 rm)^T [+bias]
// WR_ x WC_ waves (64*WR_*WC_ threads). global_load_lds staging, XOR-swizzled
// LDS chunks (proven 2-barrier structure; only tile/wave geometry templated).
// MODE 0: C = acc + bias[n]
// MODE 2: fused LSTM epilogue (requires WC_==1, WNT==64): the 4 N-fragments
//         of a thread are gates i,f,g,o of one j (Wg rows pre-reordered as
//         row' = (j>>4)*64 + gate*16 + (j&15)). Updates cstate, writes bf16 h
//         into hdst (Abuf h-region).
// MODE 3: split-K partial store: C[(bz*N_ROWS + m)*ldc + n] = acc  (no atomics)
// MODE 4: z = acc + bias stored as fp16 into C, plus per-64-col (max,sumexp)
//         stats partials (requires WNT==64). THEN: per-y-group last-block-done
//         ticket (cross-block fence+atomic) folds this y-group's rows' stats
//         into lse (cstate reused as lse-out; hdst reused as int* ticket[2]).
// MODE 5: MODE 3 epilogue + fused softmax-finish A-staging: A is fp16 z
//         (ld=lda). Per A-element (read exactly once across the split-K grid):
//         lp = z - lsep[row]; write lp (logp) to outdst; stage bf16 exp(lp)
//         into the same swizzled LDS slot gload_lds would have used.
template<int TBM, int TBN, int WR_, int WC_, int MODE>
__global__ __launch_bounds__(WR_ * WC_ * 64) void k_gemm(
    const short* __restrict__ A, int lda,
    const short* __restrict__ B, int ldb,
    const float* __restrict__ bias,
    float* __restrict__ C, size_t ldc, int Kc,
    float2* __restrict__ stats,
    float* __restrict__ cstate, short* __restrict__ hdst,
    float* __restrict__ outdst, size_t ldout, const float* __restrict__ lsep)
{
    constexpr int NW = WR_ * WC_;
    constexpr int WMT = TBM / WR_, WNT = TBN / WC_;
    constexpr int WM = WMT / 16, WN = WNT / 16;
    __shared__ short As[TBM * 64];
    __shared__ short Bs[TBN * 64];
    const int tid = threadIdx.x;
    const int lane = tid & 63, wid = tid >> 6;
    const int wr = wid % WR_, wc = wid / WR_;
    const int quad = lane >> 4, l16 = lane & 15;
    const int m0 = blockIdx.y * TBM, n0 = blockIdx.x * TBN;
    const int kbase = blockIdx.z * Kc;
    // staging lane geometry: 8 rows/instr, 8 chunks of 8 bf16 per row, XOR swizzle
    const int lrow = lane >> 3;
    const int lsw  = ((lane & 7) ^ lrow) * 8;

    f32x4 acc[WM][WN];
#pragma unroll
    for (int i = 0; i < WM; ++i)
#pragma unroll
        for (int j = 0; j < WN; ++j)
#pragma unroll
            for (int r = 0; r < 4; ++r) acc[i][j][r] = 0.0f;

    for (int kt = 0; kt < Kc; kt += TBK) {
        const int k0 = kbase + kt;
        if constexpr (MODE == 5) {
            // B first (async, in flight under the A VALU work)
#pragma unroll
            for (int ch = wid; ch < TBN / 8; ch += NW)
                gload_lds(&B[(size_t)(n0 + ch * 8 + lrow) * ldb + k0 + lsw], &Bs[ch * 512]);
            const _Float16* Z = (const _Float16*)A;
#pragma unroll
            for (int ch = wid; ch < TBM / 8; ch += NW) {
                const int row = m0 + ch * 8 + lrow;
                const int col = k0 + lsw;
                f16x8 zv = *(const f16x8*)&Z[(size_t)row * lda + col];
                const float l = lsep[row];
                float lp[8];
#pragma unroll
                for (int q = 0; q < 8; ++q) lp[q] = (float)zv[q] - l;
                float4* od = (float4*)&outdst[(size_t)row * ldout + col];
                od[0] = make_float4(lp[0], lp[1], lp[2], lp[3]);
                od[1] = make_float4(lp[4], lp[5], lp[6], lp[7]);
                bf16x8 p;
#pragma unroll
                for (int q = 0; q < 8; ++q) p[q] = f2b(__expf(lp[q]));
                *(bf16x8*)&As[ch * 512 + lane * 8] = p;
            }
        } else {
#pragma unroll
            for (int ch = wid; ch < TBM / 8; ch += NW)
                gload_lds(&A[(size_t)(m0 + ch * 8 + lrow) * lda + k0 + lsw], &As[ch * 512]);
#pragma unroll
            for (int ch = wid; ch < TBN / 8; ch += NW)
                gload_lds(&B[(size_t)(n0 + ch * 8 + lrow) * ldb + k0 + lsw], &Bs[ch * 512]);
        }
        __syncthreads();
#pragma unroll
        for (int ks = 0; ks < 2; ++ks) {
            bf16x8 af[WM], bfv[WN];
#pragma unroll
            for (int i = 0; i < WM; ++i) {
                int rr = wr * WMT + i * 16 + l16;
                af[i] = *(const bf16x8*)&As[rr * 64 + (((ks * 4 + quad) ^ (l16 & 7)) * 8)];
            }
#pragma unroll
            for (int j = 0; j < WN; ++j) {
                int rr = wc * WNT + j * 16 + l16;
                bfv[j] = *(const bf16x8*)&Bs[rr * 64 + (((ks * 4 + quad) ^ (l16 & 7)) * 8)];
            }
#pragma unroll
            for (int i = 0; i < WM; ++i)
#pragma unroll
                for (int j = 0; j < WN; ++j)
                    acc[i][j] = __builtin_amdgcn_mfma_f32_16x16x32_bf16(af[i], bfv[j], acc[i][j], 0, 0, 0);
        }
        __syncthreads();
    }

    // epilogue. C frag layout: row = quad*4 + reg, col = l16
    if constexpr (MODE == 3 || MODE == 5) {
        float* Cp = C + (size_t)blockIdx.z * N_ROWS * ldc;
#pragma unroll
        for (int i = 0; i < WM; ++i)
#pragma unroll
            for (int j = 0; j < WN; ++j) {
                const int n = n0 + wc * WNT + j * 16 + l16;
#pragma unroll
                for (int r = 0; r < 4; ++r) {
                    const int m = m0 + wr * WMT + i * 16 + quad * 4 + r;
                    Cp[(size_t)m * ldc + n] = acc[i][j][r];
                }
            }
    } else if constexpr (MODE == 2) {
        // fused LSTM cell: fragments j=0..3 are gates i,f,g,o of column jj
        float bv[WN];
#pragma unroll
        for (int j = 0; j < WN; ++j) bv[j] = bias[n0 + j * 16 + l16];
        const int jj = (n0 >> 2) + l16;   // n0 = bx*64 -> j base = bx*16
#pragma unroll
        for (int i = 0; i < WM; ++i) {
#pragma unroll
            for (int r = 0; r < 4; ++r) {
                const int m = m0 + wr * WMT + i * 16 + quad * 4 + r;
                float gi = acc[i][0][r] + bv[0];
                float gf = acc[i][1][r] + bv[1];
                float gg = acc[i][2][r] + bv[2];
                float go = acc[i][3][r] + bv[3];
                float i_ = 1.0f / (1.0f + expf(-gi));
                float f_ = 1.0f / (1.0f + expf(-gf));
                float g_ = tanhf(gg);
                float o_ = 1.0f / (1.0f + expf(-go));
                const size_t ci = (size_t)m * H_DIM + jj;
                float cn = f_ * cstate[ci] + i_ * g_;
                cstate[ci] = cn;
                hdst[(size_t)m * IN_LD + (D_IN + E_EMB) + jj] = f2b(o_ * tanhf(cn));
            }
        }
    } else if constexpr (MODE == 4) {
        _Float16* Ch = (_Float16*)C;
        float bv[WN];
#pragma unroll
        for (int j = 0; j < WN; ++j) bv[j] = bias[n0 + wc * WNT + j * 16 + l16];
#pragma unroll
        for (int i = 0; i < WM; ++i) {
            float rm[4] = {-1e30f, -1e30f, -1e30f, -1e30f};
            float rs[4] = {0.f, 0.f, 0.f, 0.f};
#pragma unroll
            for (int j = 0; j < WN; ++j)
#pragma unroll
                for (int r = 0; r < 4; ++r)
                    rm[r] = fmaxf(rm[r], acc[i][j][r] + bv[j]);
#pragma unroll
            for (int j = 0; j < WN; ++j) {
                const int n = n0 + wc * WNT + j * 16 + l16;
#pragma unroll
                for (int r = 0; r < 4; ++r) {
                    const int m = m0 + wr * WMT + i * 16 + quad * 4 + r;
                    float z = acc[i][j][r] + bv[j];
                    rs[r] += __expf(z - rm[r]);
                    Ch[(size_t)m * ldc + n] = (_Float16)z;
                }
            }
            // merge (max,sum) across the 16 l16-lanes of this quad
#pragma unroll
            for (int mask = 1; mask < 16; mask <<= 1) {
#pragma unroll
                for (int r = 0; r < 4; ++r) {
                    float om = __shfl_xor(rm[r], mask);
                    float os = __shfl_xor(rs[r], mask);
                    float nm = fmaxf(rm[r], om);
                    rs[r] = rs[r] * __expf(rm[r] - nm) + os * __expf(om - nm);
                    rm[r] = nm;
                }
            }
            if (l16 == 0) {
                const int seg = (n0 + wc * WNT) >> 6;
#pragma unroll
                for (int r = 0; r < 4; ++r) {
                    const int m = m0 + wr * WMT + i * 16 + quad * 4 + r;
                    stats[(size_t)m * SEGSTRIDE + seg] = make_float2(rm[r], rs[r]);
                }
            }
        }
        // -------- per-y-group lse fold (last-block-done) --------
        // hdst = (int*)ticket[gridDim.y]; cstate = lse out (N_ROWS floats).
        int* tick = (int*)hdst;
        float* lseout = cstate;
        __threadfence();
        __shared__ int lastFlag;
        if (tid == 0)
            lastFlag = (atomicAdd(&tick[blockIdx.y], 1) == (int)gridDim.x - 1);
        __syncthreads();
        if (lastFlag) {
            if (tid == 0) atomicExch(&tick[blockIdx.y], 0);  // reset for next step
            __threadfence();
            float2* pm = (float2*)As;              // reuse dead LDS (32 KB >= 4 KB)
            const int n = m0 + (tid & (TBM - 1));  // this y-group's rows
            const int half = tid / TBM;            // 0/1: split 500 segs in two
            float fm2[2] = {-1e30f, -1e30f}, fs2[2] = {0.f, 0.f};
            const int sgbase = half * 250;
            for (int sg = sgbase; sg < sgbase + 250; sg += 2) {
#pragma unroll
                for (int q = 0; q < 2; ++q) {
                    float2 p = stats[(size_t)n * SEGSTRIDE + sg + q];
                    float nm = fmaxf(fm2[q], p.x);
                    fs2[q] = fs2[q] * __expf(fm2[q] - nm) + p.y * __expf(p.x - nm);
                    fm2[q] = nm;
                }
            }
            float M1 = fmaxf(fm2[0], fm2[1]);
            float S1 = fs2[0] * __expf(fm2[0] - M1) + fs2[1] * __expf(fm2[1] - M1);
            pm[tid] = make_float2(M1, S1);
            __syncthreads();
            if (half == 0) {
                float2 a = pm[tid], b = pm[tid + TBM];
                float M = fmaxf(a.x, b.x);
                float S = a.y * __expf(a.x - M) + b.y * __expf(b.x - M);
                lseout[n] = M + __logf(S);
            }
        }
    } else {
        float bv[WN];
#pragma unroll
        for (int j = 0; j < WN; ++j) bv[j] = bias[n0 + wc * WNT + j * 16 + l16];
#pragma unroll
        for (int i = 0; i < WM; ++i)
#pragma unroll
            for (int j = 0; j < WN; ++j) {
                const int n = n0 + wc * WNT + j * 16 + l16;
#pragma unroll
                for (int r = 0; r < 4; ++r) {
                    const int m = m0 + wr * WMT + i * 16 + quad * 4 + r;
                    C[(size_t)m * ldc + n] = acc[i][j][r] + bv[j];
                }
            }
    }
}

// ---------------------------------------------------------------------------
// per-launch prep: bf16 weight packs + Abuf init + c zero + lse-ticket init.
// Wg/bsum are REORDERED for the fused-LSTM gates GEMM:
//   row' = (j>>4)*64 + gate*16 + (j&15), orig row g = gate*512 + j
__global__ __launch_bounds__(256) void k_prep(
    const float* __restrict__ x, const float* __restrict__ emb_table,
    const float* __restrict__ W_ih, const float* __restrict__ W_hh,
    const float* __restrict__ b_ih, const float* __restrict__ b_hh,
    const float* __restrict__ W_out,
    short* __restrict__ Abuf, short* __restrict__ Wg, float* __restrict__ bsum,
    short* __restrict__ Wout16, float* __restrict__ c, int* __restrict__ ticket)
{
    const int idx0 = blockIdx.x * 256 + threadIdx.x;
    const int gs = gridDim.x * 256;
    if (idx0 < 4) ticket[idx0] = 0;
    const float4* W4 = (const float4*)W_out;
    for (int i = idx0; i < V_DIM * H_DIM / 4; i += gs) {
        float4 v = W4[i];
        short4 o;
        o.x = f2b(v.x); o.y = f2b(v.y); o.z = f2b(v.z); o.w = f2b(v.w);
        ((short4*)Wout16)[i] = o;
    }
    for (int i = idx0; i < G_DIM * IN_LD; i += gs) {
        int rp = i / IN_LD, k = i - rp * IN_LD;
        int j = ((rp >> 6) << 4) | (rp & 15);
        int gate = (rp >> 4) & 3;
        int g = gate * H_DIM + j;
        float v = (k < D_IN + E_EMB) ? W_ih[(size_t)g * (D_IN + E_EMB) + k]
                                     : W_hh[(size_t)g * H_DIM + (k - (D_IN + E_EMB))];
        Wg[i] = f2b(v);
    }
    for (int i = idx0; i < G_DIM; i += gs) {
        int j = ((i >> 6) << 4) | (i & 15);
        int gate = (i >> 4) & 3;
        int g = gate * H_DIM + j;
        bsum[i] = b_ih[g] + b_hh[g];
    }
    for (int i = idx0; i < N_ROWS * IN_LD; i += gs) {
        int n = i / IN_LD, col = i - n * IN_LD;
        float v;
        if (col < D_IN)              v = x[(size_t)n * D_IN + col];
        else if (col < D_IN + E_EMB) v = emb_table[(size_t)OOV_ID * E_EMB + (col - D_IN)];
        else                         v = 0.0f;
        Abuf[i] = f2b(v);
    }
    for (int i = idx0; i < N_ROWS * H_DIM; i += gs) c[i] = 0.0f;
}

// ---------------------------------------------------------------------------
// emb_T[e][v] = bf16(emb_table[v][e])  (256 x 32000)
__global__ __launch_bounds__(256) void k_trans(const float* __restrict__ emb,
                                               short* __restrict__ embT)
{
    __shared__ float tile[64][65];
    const int v0 = blockIdx.x * 64, e0 = blockIdx.y * 64;
    const int tid = threadIdx.x;
#pragma unroll
    for (int i = 0; i < 16; ++i) {
        int idx = tid + i * 256;
        int vr = idx >> 6, ec = idx & 63;
        tile[vr][ec] = emb[(size_t)(v0 + vr) * E_EMB + e0 + ec];
    }
    __syncthreads();
#pragma unroll
    for (int i = 0; i < 16; ++i) {
        int idx = tid + i * 256;
        int er = idx >> 6, vc = idx & 63;
        embT[(size_t)(e0 + er) * V_DIM + v0 + vc] = f2b(tile[vc][er]);
    }
}

// ---------------------------------------------------------------------------
// reduce split-K emb partials -> bf16 into Abuf[:,512:768)  (float4 lanes)
__global__ __launch_bounds__(256) void k_embred(const float* __restrict__ ep,
                                                short* __restrict__ Abuf)
{
    int idx = blockIdx.x * 256 + threadIdx.x;       // N_ROWS*E_EMB/4 total
    int n = idx >> 6, e4 = idx & 63;                // e4: float4 index in row
    const float4* ep4 = (const float4*)ep;
    float4 s0 = make_float4(0.f, 0.f, 0.f, 0.f), s1 = s0;
#pragma unroll 2
    for (int z = 0; z < EMB_SPLIT; z += 2) {
        float4 a = ep4[(((size_t)z * N_ROWS + n) * E_EMB >> 2) + e4];
        float4 b = ep4[(((size_t)(z + 1) * N_ROWS + n) * E_EMB >> 2) + e4];
        s0.x += a.x; s0.y += a.y; s0.z += a.z; s0.w += a.w;
        s1.x += b.x; s1.y += b.y; s1.z += b.z; s1.w += b.w;
    }
    short4 o;
    o.x = f2b(s0.x + s1.x); o.y = f2b(s0.y + s1.y);
    o.z = f2b(s0.z + s1.z); o.w = f2b(s0.w + s1.w);
    *(short4*)&Abuf[(size_t)n * IN_LD + D_IN + e4 * 4] = o;
}

// ---------------------------------------------------------------------------
// final-step finish: out = fp16 z - lse[row] (fp32). No prob feed.
__global__ __launch_bounds__(256) void k_finish(const _Float16* __restrict__ zbuf,
                                                float* __restrict__ out,
                                                const float* __restrict__ lse,
                                                int step)
{
    const int n = blockIdx.y;
    const float l = lse[n];
    const f16x8* zr = (const f16x8*)(zbuf + (size_t)n * V_DIM);
    float4* row4 = (float4*)(out + ((size_t)n * K_STEPS + step) * V_DIM);
#pragma unroll
    for (int it = 0; it < 2; ++it) {
        const int slot = threadIdx.x + it * 256;
        if (slot < 500) {
            const int cidx = blockIdx.x * 500 + slot;
            f16x8 zv = zr[cidx];
            float lp[8];
#pragma unroll
            for (int k = 0; k < 8; ++k) lp[k] = (float)zv[k] - l;
            row4[cidx * 2]     = make_float4(lp[0], lp[1], lp[2], lp[3]);
            row4[cidx * 2 + 1] = make_float4(lp[4], lp[5], lp[6], lp[7]);
        }
    }
}

// ---------------------------------------------------------------------------
extern "C" void kernel_launch(void* const* d_in, const int* in_sizes, int n_in,
                              void* d_out, int out_size, void* d_ws, size_t ws_size,
                              hipStream_t stream) {
    (void)in_sizes; (void)n_in; (void)out_size; (void)ws_size;
    const float* x       = (const float*)d_in[0];
    const float* emb_tab = (const float*)d_in[2];
    const float* W_ih    = (const float*)d_in[3];
    const float* b_ih    = (const float*)d_in[4];
    const float* W_hh    = (const float*)d_in[5];
    const float* b_hh    = (const float*)d_in[6];
    const float* W_out   = (const float*)d_in[7];
    const float* b_out   = (const float*)d_in[8];
    float* out = (float*)d_out;

    // workspace carve (~160 MB; ws is ~1 GB per harness poison fill)
    char* ws = (char*)d_ws;
    short* Abuf   = (short*)ws;  ws += (size_t)N_ROWS * IN_LD * sizeof(short);
    float* c      = (float*)ws;  ws += (size_t)N_ROWS * H_DIM * sizeof(float);
    short* Wout16 = (short*)ws;  ws += (size_t)V_DIM * H_DIM * sizeof(short);
    short* Wg     = (short*)ws;  ws += (size_t)G_DIM * IN_LD * sizeof(short);
    float* bsum   = (float*)ws;  ws += (size_t)G_DIM * sizeof(float);
    short* embT   = (short*)ws;  ws += (size_t)E_EMB * V_DIM * sizeof(short);
    float2* stats = (float2*)ws; ws += (size_t)N_ROWS * SEGSTRIDE * sizeof(float2);
    float* lse    = (float*)ws;  ws += (size_t)N_ROWS * sizeof(float);
    int* ticket   = (int*)ws;    ws += 256;
    ws = (char*)(((size_t)ws + 255) & ~(size_t)255);
    _Float16* zbuf = (_Float16*)ws; ws += (size_t)N_ROWS * V_DIM * sizeof(_Float16);
    float* epart   = (float*)ws;    ws += (size_t)EMB_SPLIT * N_ROWS * E_EMB * sizeof(float);

    k_prep<<<2048, 256, 0, stream>>>(x, emb_tab, W_ih, W_hh, b_ih, b_hh, W_out,
                                     Abuf, Wg, bsum, Wout16, c, ticket);
    k_trans<<<dim3(V_DIM / 64, E_EMB / 64), 256, 0, stream>>>(emb_tab, embT);

    for (int t = 0; t < K_STEPS; ++t) {
        if (t > 0) {
            // fused: logp(t-1) write + probs + emb GEMM (split-K partials)
            k_gemm<128, 256, 2, 4, 5><<<dim3(1, N_ROWS / 128, EMB_SPLIT), 512, 0, stream>>>(
                (const short*)zbuf, V_DIM, embT, V_DIM, nullptr, epart, E_EMB, EMB_CHUNK,
                nullptr, nullptr, nullptr,
                out + (size_t)(t - 1) * V_DIM, (size_t)K_STEPS * V_DIM, lse);
            k_embred<<<N_ROWS * E_EMB / 4 / 256, 256, 0, stream>>>(epart, Abuf);
        }
        // gates GEMM (full K=1280) + fused LSTM -> c, h
        k_gemm<64, 64, 4, 1, 2><<<dim3(G_DIM / 64, N_ROWS / 64, 1), 256, 0, stream>>>(
            Abuf, IN_LD, Wg, IN_LD, bsum, nullptr, 0, IN_LD, nullptr, c, Abuf,
            nullptr, 0, nullptr);
        // logits: h @ Wout16^T + b_out -> zbuf fp16 + stats + in-kernel lse fold
        k_gemm<256, 128, 4, 2, 4><<<dim3(V_DIM / 128, N_ROWS / 256, 1), 512, 0, stream>>>(
            Abuf + (D_IN + E_EMB), IN_LD, Wout16, H_DIM, b_out,
            (float*)zbuf, V_DIM, H_DIM, stats, lse, (short*)ticket,
            nullptr, 0, nullptr);
    }
    // final step: plain finish (no feed); lse already folded by logits kernel
    k_finish<<<dim3(8, N_ROWS), 256, 0, stream>>>(zbuf, out, lse, K_STEPS - 1);
}